// Round 1
// baseline (178.508 us; speedup 1.0000x reference)
//
#include <hip/hip_runtime.h>
#include <hip/hip_bf16.h>

// MHA forward: B=4, S=2048, D=512, H=8, HD=64.
// Pipeline: [fused QKV proj GEMM, bf16 ws] -> [flash attn] -> [out proj, fp32].
// ws layout: Qb[8M] Kb[8M] Vt[8M] Ctx[8M] bytes (bf16).

#define BB 4
#define SS 2048
#define DD 512
#define HH 8
#define HDD 64

typedef __bf16 bf16;
typedef __bf16 bf16x8 __attribute__((ext_vector_type(8)));
typedef float f32x4 __attribute__((ext_vector_type(4)));

// LDS tile rows are 128 bytes; XOR-swizzle 16B slots with row&7 (T2 / G4 recipe)
__device__ __forceinline__ int swz(int row, int byteInRow) {
    return row * 128 + (byteInRow ^ ((row & 7) << 4));
}

// ---------------- fused QKV projection: out = X @ W^T + b (bf16 out) ----------------
// z=0: Q -> Qb[M][D]; z=1: K -> Kb[M][D]; z=2: V -> Vt[B][H][HD][S] (transposed)
__global__ __launch_bounds__(256) void gemm_qkv(
    const float* __restrict__ Xq, const float* __restrict__ Xk, const float* __restrict__ Xv,
    const float* __restrict__ Wq, const float* __restrict__ Wk, const float* __restrict__ Wv,
    const float* __restrict__ bq, const float* __restrict__ bk, const float* __restrict__ bv,
    bf16* __restrict__ Qb, bf16* __restrict__ Kb, bf16* __restrict__ Vt)
{
    const int z = blockIdx.z;
    const float* __restrict__ A    = (z == 0) ? Xq : (z == 1) ? Xk : Xv;
    const float* __restrict__ W    = (z == 0) ? Wq : (z == 1) ? Wk : Wv;
    const float* __restrict__ bias = (z == 0) ? bq : (z == 1) ? bk : bv;

    __shared__ char lds[32768];
    char* As = lds;             // [128][64] bf16, swizzled
    char* Bs = lds + 16384;     // [128][64] bf16, swizzled

    const int t = threadIdx.x, wid = t >> 6, lane = t & 63;
    const int m0 = blockIdx.y * 128, n0 = blockIdx.x * 128;
    const int wr = wid >> 1, wc = wid & 1;
    const int lr = lane & 15, lg = lane >> 4;

    float bv4[4];
#pragma unroll
    for (int ni = 0; ni < 4; ni++) bv4[ni] = bias[n0 + wc * 64 + ni * 16 + lr];

    f32x4 acc[4][4] = {};

    for (int k0 = 0; k0 < DD; k0 += 64) {
#pragma unroll
        for (int i = 0; i < 8; i++) {
            int g = t + i * 256;           // float4 granule, 2048 total per tile
            int row = g >> 4, c4 = g & 15;
            float4 va = *(const float4*)&A[(size_t)(m0 + row) * DD + k0 + c4 * 4];
            float4 vb = *(const float4*)&W[(size_t)(n0 + row) * DD + k0 + c4 * 4];
            union { bf16 h[4]; ushort4 u; } ca, cb;
            ca.h[0] = (bf16)va.x; ca.h[1] = (bf16)va.y; ca.h[2] = (bf16)va.z; ca.h[3] = (bf16)va.w;
            cb.h[0] = (bf16)vb.x; cb.h[1] = (bf16)vb.y; cb.h[2] = (bf16)vb.z; cb.h[3] = (bf16)vb.w;
            *(ushort4*)(As + swz(row, c4 * 8)) = ca.u;
            *(ushort4*)(Bs + swz(row, c4 * 8)) = cb.u;
        }
        __syncthreads();
#pragma unroll
        for (int kk = 0; kk < 2; kk++) {
            bf16x8 af[4], bfr[4];
#pragma unroll
            for (int mi = 0; mi < 4; mi++)
                af[mi] = *(const bf16x8*)(As + swz(wr * 64 + mi * 16 + lr, kk * 64 + lg * 16));
#pragma unroll
            for (int ni = 0; ni < 4; ni++)
                bfr[ni] = *(const bf16x8*)(Bs + swz(wc * 64 + ni * 16 + lr, kk * 64 + lg * 16));
#pragma unroll
            for (int mi = 0; mi < 4; mi++)
#pragma unroll
                for (int ni = 0; ni < 4; ni++)
                    acc[mi][ni] = __builtin_amdgcn_mfma_f32_16x16x32_bf16(af[mi], bfr[ni], acc[mi][ni], 0, 0, 0);
        }
        __syncthreads();
    }

#pragma unroll
    for (int mi = 0; mi < 4; mi++)
#pragma unroll
        for (int ni = 0; ni < 4; ni++) {
            int col = n0 + wc * 64 + ni * 16 + lr;
#pragma unroll
            for (int j = 0; j < 4; j++) {
                int row = m0 + wr * 64 + mi * 16 + lg * 4 + j;   // C layout: col=lane&15, row=(lane>>4)*4+j
                float v = acc[mi][ni][j] + bv4[ni];
                if (z == 0) {
                    Qb[(size_t)row * DD + col] = (bf16)v;
                } else if (z == 1) {
                    Kb[(size_t)row * DD + col] = (bf16)v;
                } else {
                    int b = row >> 11, s = row & 2047, h = col >> 6, d = col & 63;
                    Vt[((((size_t)b * HH + h) * HDD + d) << 11) + s] = (bf16)v;
                }
            }
        }
}

// ---------------- flash attention ----------------
// grid: (S/64 qtiles, B*H). 4 waves; wave owns 16 q rows. KVBLK=64.
__global__ __launch_bounds__(256) void attn_kernel(
    const bf16* __restrict__ Qb, const bf16* __restrict__ Kb,
    const bf16* __restrict__ Vt, bf16* __restrict__ Ctx)
{
    __shared__ char lds[24576];
    char* Ks = lds;                  // [64][64] bf16 swizzled (rows = kv)
    char* Vs = lds + 8192;           // [64][64] bf16 swizzled (rows = d, cols = kv)
    const int t = threadIdx.x, wid = t >> 6, lane = t & 63;
    char* Ps = lds + 16384 + wid * 2048;   // per-wave P [16][64] bf16 swizzled
    const int lr = lane & 15, lg = lane >> 4;
    const int b = blockIdx.y >> 3, h = blockIdx.y & 7;
    const int q0 = blockIdx.x * 64 + wid * 16;

    const bf16* Qp = Qb + ((size_t)b * SS + q0) * DD + h * HDD;
    const bf16* Kp = Kb + (size_t)b * SS * DD + h * HDD;
    const bf16* Vp = Vt + ((size_t)b * HH + h) * HDD * SS;

    bf16x8 qf[2];
#pragma unroll
    for (int kk = 0; kk < 2; kk++)
        qf[kk] = *(const bf16x8*)(Qp + (size_t)lr * DD + kk * 32 + lg * 8);

    float m_r[4], l_r[4];
    f32x4 ctx[4] = {};
#pragma unroll
    for (int j = 0; j < 4; j++) { m_r[j] = -1e30f; l_r[j] = 0.f; }

    for (int kv0 = 0; kv0 < SS; kv0 += 64) {
#pragma unroll
        for (int i = 0; i < 2; i++) {
            int g = t + i * 256;
            int row = g >> 3, sl = g & 7;
            *(uint4*)(Ks + swz(row, sl * 16)) = *(const uint4*)(Kp + (size_t)(kv0 + row) * DD + sl * 8);
            *(uint4*)(Vs + swz(row, sl * 16)) = *(const uint4*)(Vp + (size_t)row * SS + kv0 + sl * 8);
        }
        __syncthreads();

        f32x4 sc[4] = {};
#pragma unroll
        for (int nt = 0; nt < 4; nt++)
#pragma unroll
            for (int kk = 0; kk < 2; kk++) {
                bf16x8 kf = *(const bf16x8*)(Ks + swz(nt * 16 + lr, kk * 64 + lg * 16));
                sc[nt] = __builtin_amdgcn_mfma_f32_16x16x32_bf16(qf[kk], kf, sc[nt], 0, 0, 0);
            }

        // wave-parallel online softmax; row r=(lane>>4)*4+j lives on 16 lanes
#pragma unroll
        for (int j = 0; j < 4; j++) {
#pragma unroll
            for (int nt = 0; nt < 4; nt++) sc[nt][j] *= 0.125f;
            float v = fmaxf(fmaxf(sc[0][j], sc[1][j]), fmaxf(sc[2][j], sc[3][j]));
#pragma unroll
            for (int o = 1; o < 16; o <<= 1) v = fmaxf(v, __shfl_xor(v, o));
            float mn = fmaxf(m_r[j], v);
            float corr = __expf(m_r[j] - mn);
            m_r[j] = mn;
            float s = 0.f;
#pragma unroll
            for (int nt = 0; nt < 4; nt++) { float p = __expf(sc[nt][j] - mn); sc[nt][j] = p; s += p; }
#pragma unroll
            for (int o = 1; o < 16; o <<= 1) s += __shfl_xor(s, o);
            l_r[j] = l_r[j] * corr + s;
#pragma unroll
            for (int dt = 0; dt < 4; dt++) ctx[dt][j] *= corr;
        }

        // P (C-layout) -> LDS bf16, then re-read as A fragments
#pragma unroll
        for (int nt = 0; nt < 4; nt++)
#pragma unroll
            for (int j = 0; j < 4; j++)
                *(bf16*)(Ps + swz(lg * 4 + j, (nt * 16 + lr) * 2)) = (bf16)sc[nt][j];

#pragma unroll
        for (int kk = 0; kk < 2; kk++) {
            bf16x8 pf = *(const bf16x8*)(Ps + swz(lr, kk * 64 + lg * 16));
#pragma unroll
            for (int dt = 0; dt < 4; dt++) {
                bf16x8 vf = *(const bf16x8*)(Vs + swz(dt * 16 + lr, kk * 64 + lg * 16));
                ctx[dt] = __builtin_amdgcn_mfma_f32_16x16x32_bf16(pf, vf, ctx[dt], 0, 0, 0);
            }
        }
        __syncthreads();
    }

#pragma unroll
    for (int dt = 0; dt < 4; dt++)
#pragma unroll
        for (int j = 0; j < 4; j++) {
            int qrow = q0 + lg * 4 + j;
            int col = h * HDD + dt * 16 + lr;
            Ctx[((size_t)b * SS + qrow) * DD + col] = (bf16)(ctx[dt][j] / l_r[j]);
        }
}

// ---------------- output projection: out = Ctx @ Wo^T + bo (fp32 out) ----------------
__global__ __launch_bounds__(256) void gemm_out(
    const bf16* __restrict__ A, const float* __restrict__ W,
    const float* __restrict__ bias, float* __restrict__ Out)
{
    __shared__ char lds[32768];
    char* As = lds;
    char* Bs = lds + 16384;

    const int t = threadIdx.x, wid = t >> 6, lane = t & 63;
    const int m0 = blockIdx.y * 128, n0 = blockIdx.x * 128;
    const int wr = wid >> 1, wc = wid & 1;
    const int lr = lane & 15, lg = lane >> 4;

    float bv4[4];
#pragma unroll
    for (int ni = 0; ni < 4; ni++) bv4[ni] = bias[n0 + wc * 64 + ni * 16 + lr];

    f32x4 acc[4][4] = {};

    for (int k0 = 0; k0 < DD; k0 += 64) {
        // stage A (bf16 source): 16B granules
#pragma unroll
        for (int i = 0; i < 4; i++) {
            int g = t + i * 256;
            int row = g >> 3, sl = g & 7;
            *(uint4*)(As + swz(row, sl * 16)) = *(const uint4*)&A[(size_t)(m0 + row) * DD + k0 + sl * 8];
        }
        // stage W (fp32 source) with convert
#pragma unroll
        for (int i = 0; i < 8; i++) {
            int g = t + i * 256;
            int row = g >> 4, c4 = g & 15;
            float4 vb = *(const float4*)&W[(size_t)(n0 + row) * DD + k0 + c4 * 4];
            union { bf16 h[4]; ushort4 u; } cb;
            cb.h[0] = (bf16)vb.x; cb.h[1] = (bf16)vb.y; cb.h[2] = (bf16)vb.z; cb.h[3] = (bf16)vb.w;
            *(ushort4*)(Bs + swz(row, c4 * 8)) = cb.u;
        }
        __syncthreads();
#pragma unroll
        for (int kk = 0; kk < 2; kk++) {
            bf16x8 af[4], bfr[4];
#pragma unroll
            for (int mi = 0; mi < 4; mi++)
                af[mi] = *(const bf16x8*)(As + swz(wr * 64 + mi * 16 + lr, kk * 64 + lg * 16));
#pragma unroll
            for (int ni = 0; ni < 4; ni++)
                bfr[ni] = *(const bf16x8*)(Bs + swz(wc * 64 + ni * 16 + lr, kk * 64 + lg * 16));
#pragma unroll
            for (int mi = 0; mi < 4; mi++)
#pragma unroll
                for (int ni = 0; ni < 4; ni++)
                    acc[mi][ni] = __builtin_amdgcn_mfma_f32_16x16x32_bf16(af[mi], bfr[ni], acc[mi][ni], 0, 0, 0);
        }
        __syncthreads();
    }

#pragma unroll
    for (int mi = 0; mi < 4; mi++)
#pragma unroll
        for (int ni = 0; ni < 4; ni++) {
            int col = n0 + wc * 64 + ni * 16 + lr;
#pragma unroll
            for (int j = 0; j < 4; j++) {
                int row = m0 + wr * 64 + mi * 16 + lg * 4 + j;
                Out[(size_t)row * DD + col] = acc[mi][ni][j] + bv4[ni];
            }
        }
}

extern "C" void kernel_launch(void* const* d_in, const int* in_sizes, int n_in,
                              void* d_out, int out_size, void* d_ws, size_t ws_size,
                              hipStream_t stream) {
    (void)in_sizes; (void)n_in; (void)out_size; (void)ws_size;
    const float* q  = (const float*)d_in[0];
    const float* k  = (const float*)d_in[1];
    const float* v  = (const float*)d_in[2];
    const float* Wq = (const float*)d_in[3]; const float* bq = (const float*)d_in[4];
    const float* Wk = (const float*)d_in[5]; const float* bk = (const float*)d_in[6];
    const float* Wv = (const float*)d_in[7]; const float* bv = (const float*)d_in[8];
    const float* Wo = (const float*)d_in[9]; const float* bo = (const float*)d_in[10];
    float* out = (float*)d_out;

    char* ws = (char*)d_ws;
    const size_t MD2 = (size_t)BB * SS * DD * 2;   // 8 MiB per bf16 [M][D] buffer
    bf16* Qb  = (bf16*)(ws);
    bf16* Kb  = (bf16*)(ws + MD2);
    bf16* Vt  = (bf16*)(ws + 2 * MD2);
    bf16* Ctx = (bf16*)(ws + 3 * MD2);

    dim3 gQKV(DD / 128, (BB * SS) / 128, 3);       // (4, 64, 3)
    gemm_qkv<<<gQKV, 256, 0, stream>>>(q, k, v, Wq, Wk, Wv, bq, bk, bv, Qb, Kb, Vt);

    dim3 gA(SS / 64, BB * HH);                      // (32, 32)
    attn_kernel<<<gA, 256, 0, stream>>>(Qb, Kb, Vt, Ctx);

    dim3 gO(DD / 128, (BB * SS) / 128);             // (4, 64)
    gemm_out<<<gO, 256, 0, stream>>>(Ctx, Wo, bo, out);
}